// Round 16
// baseline (460.224 us; speedup 1.0000x reference)
//
#include <hip/hip_runtime.h>
#include <cstdint>
#include <cstddef>

typedef __bf16 bf16;
typedef __attribute__((ext_vector_type(4))) float f32x4;
typedef __attribute__((ext_vector_type(8))) __bf16 bf16x8;
typedef __attribute__((ext_vector_type(4))) __bf16 bf16x4;

static __device__ __forceinline__ f32x4 mfma16(bf16x8 a, bf16x8 b, f32x4 c) {
    return __builtin_amdgcn_mfma_f32_16x16x32_bf16(a, b, c, 0, 0, 0);
}

#define GLOAD_LDS16(gsrc, ldst)                                              \
    __builtin_amdgcn_global_load_lds(                                        \
        (const __attribute__((address_space(1))) void*)(gsrc),               \
        (__attribute__((address_space(3))) void*)(ldst), 16, 0, 0)

// load 8 consecutive elems as floats, fp32 or bf16 source
template <typename T>
static __device__ __forceinline__ void load8(const T* p, float* v) {
    if constexpr (sizeof(T) == 4) {
        const float4 a0 = *(const float4*)p;
        const float4 a1 = *(const float4*)(p + 4);
        v[0] = a0.x; v[1] = a0.y; v[2] = a0.z; v[3] = a0.w;
        v[4] = a1.x; v[5] = a1.y; v[6] = a1.z; v[7] = a1.w;
    } else {
        const bf16x8 a = *(const bf16x8*)p;
        #pragma unroll
        for (int e = 0; e < 8; ++e) v[e] = (float)a[e];
    }
}

// ---------------------------------------------------------------------------
// Fused weight transpose + cast (all 8 weights in ONE launch).
// ---------------------------------------------------------------------------
struct TransArgs {
    const float* W[8];
    bf16* Wt[8];
    int K[8];
    int N[8];
    int blk0[9];
};

__global__ __launch_bounds__(256)
void transpose_all(TransArgs a) {
    __shared__ float tile[32][33];
    const int b = blockIdx.x;
    int j = 0;
    #pragma unroll
    for (int i = 0; i < 7; ++i)
        if (b >= a.blk0[i + 1]) j = i + 1;
    const int rel = b - a.blk0[j];
    const int K = a.K[j], N = a.N[j];
    const int nxb = N >> 5;
    const int n0 = (rel % nxb) * 32, k0 = (rel / nxb) * 32;
    const float* W = a.W[j];
    bf16* Wt = a.Wt[j];
    const int tx = threadIdx.x & 31, ty = threadIdx.x >> 5;
    #pragma unroll
    for (int i = ty; i < 32; i += 8)
        tile[i][tx] = W[(size_t)(k0 + i) * N + n0 + tx];
    __syncthreads();
    #pragma unroll
    for (int i = ty; i < 32; i += 8)
        Wt[(size_t)(n0 + i) * K + k0 + tx] = (bf16)tile[tx][i];
}

// ---------------------------------------------------------------------------
// LayerNorm over 512 cols, T in (fp32/bf16) -> bf16 out. 1 wave/row.
// ---------------------------------------------------------------------------
template <typename T>
__global__ __launch_bounds__(256)
void ln_kernel(const T* __restrict__ x, const float* __restrict__ g,
               const float* __restrict__ b, bf16* __restrict__ out) {
    const int row = blockIdx.x * 4 + (threadIdx.x >> 6);
    const int lane = threadIdx.x & 63;
    float vx[8];
    load8(x + (size_t)row * 512 + lane * 8, vx);
    float s = 0.f, ss = 0.f;
    #pragma unroll
    for (int k = 0; k < 8; ++k) { s += vx[k]; ss += vx[k] * vx[k]; }
    #pragma unroll
    for (int m = 1; m < 64; m <<= 1) {
        s  += __shfl_xor(s, m);
        ss += __shfl_xor(ss, m);
    }
    const float mean = s * (1.0f / 512.0f);
    const float var  = ss * (1.0f / 512.0f) - mean * mean;
    const float inv  = rsqrtf(var + 1e-5f);
    const int c0 = lane * 8;
    const float4 g0 = *(const float4*)&g[c0], g1 = *(const float4*)&g[c0 + 4];
    const float4 b0 = *(const float4*)&b[c0], b1 = *(const float4*)&b[c0 + 4];
    const float gv[8] = {g0.x, g0.y, g0.z, g0.w, g1.x, g1.y, g1.z, g1.w};
    const float bv[8] = {b0.x, b0.y, b0.z, b0.w, b1.x, b1.y, b1.z, b1.w};
    bf16x8 o;
    #pragma unroll
    for (int k = 0; k < 8; ++k)
        o[k] = (bf16)((vx[k] - mean) * inv * gv[k] + bv[k]);
    *(bf16x8*)&out[(size_t)row * 512 + c0] = o;
}

// ---------------------------------------------------------------------------
// GEMM: 128x128 tile, BK=32, 8 waves, per-wave 64x32 (acc[4][2], 32 VGPR),
// __launch_bounds__(512,8) -> 32 waves/CU. Hybrid K (static K=512 unroll /
// runtime loop for K=2048). gload_lds(16B) + source slot swizzle, XCD block
// swizzle. Epilogues via per-wave [16][36] LDS bounce, vectorized.
// EPI 0: bf16 out. EPI 1: +bias +res -> fp32 out. EPI 2: +bias GELU bf16.
// EPI 3: +bias +res -> bf16 out. RT = res element type (float or bf16).
// ---------------------------------------------------------------------------
template <int EPI, int KT, typename RT>
__global__ __launch_bounds__(512, 8)
void gemm_bt(const bf16* __restrict__ A, const bf16* __restrict__ Bt,
             int N, int Krt, const float* __restrict__ bias,
             const RT* __restrict__ res, float* __restrict__ outf,
             bf16* __restrict__ outh) {
    const int K = (KT > 0) ? KT : Krt;
    __shared__ __align__(16) bf16 smem[16384];
    auto lsA = [&](int buf) { return smem + buf * 4096; };
    auto lsB = [&](int buf) { return smem + 8192 + buf * 4096; };
    const int nx = gridDim.x;
    const int nwg = nx * gridDim.y;
    const int flat = blockIdx.y * nx + blockIdx.x;
    const int cpx = nwg >> 3;
    const int bswz = (flat & 7) * cpx + (flat >> 3);
    const int bn = bswz % nx, bm = bswz / nx;

    const int tid = threadIdx.x, lane = tid & 63, wv = tid >> 6;
    const int wr = wv >> 2, wc = wv & 3;
    const int l15 = lane & 15, lg = lane >> 4;
    const size_t abase = (size_t)bm * 128 * K;
    const size_t bbase = (size_t)bn * 128 * K;
    const int sr = wv * 16 + (lane >> 2);
    const int ks = ((lane & 3) ^ ((sr >> 1) & 3)) * 8;
    const bf16* aSrc = &A[abase + (size_t)sr * K + ks];
    const bf16* bSrc = &Bt[bbase + (size_t)sr * K + ks];

    f32x4 acc[4][2] = {};

    auto stage = [&](int buf, int kt) {
        GLOAD_LDS16(aSrc + kt, lsA(buf) + wv * 512);
        GLOAD_LDS16(bSrc + kt, lsB(buf) + wv * 512);
    };
    auto compute = [&](int buf) {
        bf16x8 af[4], bfr[2];
        #pragma unroll
        for (int i = 0; i < 4; ++i) {
            const int r = wr * 64 + i * 16 + l15;
            af[i] = *(const bf16x8*)
                (lsA(buf) + r * 32 + ((lg ^ ((r >> 1) & 3)) * 8));
        }
        #pragma unroll
        for (int j = 0; j < 2; ++j) {
            const int r = wc * 32 + j * 16 + l15;
            bfr[j] = *(const bf16x8*)
                (lsB(buf) + r * 32 + ((lg ^ ((r >> 1) & 3)) * 8));
        }
        #pragma unroll
        for (int i = 0; i < 4; ++i)
            #pragma unroll
            for (int j = 0; j < 2; ++j)
                acc[i][j] = mfma16(af[i], bfr[j], acc[i][j]);
    };

    if constexpr (KT > 0) {
        constexpr int NK = KT >> 5;
        stage(0, 0);
        __syncthreads();
        #pragma unroll
        for (int t = 0; t < NK - 1; ++t) {
            stage((t + 1) & 1, (t + 1) * 32);
            compute(t & 1);
            __syncthreads();
        }
        compute((NK - 1) & 1);
        __syncthreads();
    } else {
        const int NK = K >> 5;
        stage(0, 0);
        __syncthreads();
        int cur = 0;
        for (int t = 0; t < NK - 1; ++t) {
            stage(cur ^ 1, (t + 1) * 32);
            compute(cur);
            __syncthreads();
            cur ^= 1;
        }
        compute(cur);
        __syncthreads();
    }

    // ---- vectorized epilogue via per-wave LDS bounce ----
    float* lsW = (float*)smem + wv * 1024;   // [16][36]
    const int orow = bm * 128 + wr * 64;
    const int ocol = bn * 128 + wc * 32;
    #pragma unroll
    for (int i = 0; i < 4; ++i) {
        #pragma unroll
        for (int r = 0; r < 4; ++r)
            #pragma unroll
            for (int j = 0; j < 2; ++j)
                lsW[(lg * 4 + r) * 36 + j * 16 + l15] = acc[i][j][r];
        __builtin_amdgcn_s_waitcnt(0);   // lgkmcnt(0): same-wave visibility
        if constexpr (EPI == 0 || EPI == 2 || EPI == 3) {
            const int rl = lane >> 2, c8 = (lane & 3) * 8;
            const float4 v0 = *(const float4*)&lsW[rl * 36 + c8];
            const float4 v1 = *(const float4*)&lsW[rl * 36 + c8 + 4];
            float vv[8] = {v0.x, v0.y, v0.z, v0.w, v1.x, v1.y, v1.z, v1.w};
            const size_t gro = (size_t)(orow + i * 16 + rl) * N + ocol + c8;
            if constexpr (EPI == 2) {
                const float4 bb0 = *(const float4*)&bias[ocol + c8];
                const float4 bb1 = *(const float4*)&bias[ocol + c8 + 4];
                const float bv[8] = {bb0.x, bb0.y, bb0.z, bb0.w,
                                     bb1.x, bb1.y, bb1.z, bb1.w};
                #pragma unroll
                for (int e = 0; e < 8; ++e) {
                    const float t = vv[e] + bv[e];
                    vv[e] = 0.5f * t * (1.0f + erff(t * 0.70710678118f));
                }
            } else if constexpr (EPI == 3) {
                const float4 bb0 = *(const float4*)&bias[ocol + c8];
                const float4 bb1 = *(const float4*)&bias[ocol + c8 + 4];
                const float bv[8] = {bb0.x, bb0.y, bb0.z, bb0.w,
                                     bb1.x, bb1.y, bb1.z, bb1.w};
                float rv[8];
                load8(res + gro, rv);
                #pragma unroll
                for (int e = 0; e < 8; ++e) vv[e] += bv[e] + rv[e];
            }
            bf16x8 o;
            #pragma unroll
            for (int e = 0; e < 8; ++e) o[e] = (bf16)vv[e];
            *(bf16x8*)&outh[gro] = o;
        } else {
            // EPI 1: fp32 out, res type RT
            const int c4 = (lane & 7) * 4;
            const float4 bb = *(const float4*)&bias[ocol + c4];
            #pragma unroll
            for (int ii = 0; ii < 2; ++ii) {
                const int rl = ii * 8 + (lane >> 3);
                const size_t gro = (size_t)(orow + i * 16 + rl) * N + ocol + c4;
                float4 v = *(const float4*)&lsW[rl * 36 + c4];
                float rr[4];
                if constexpr (sizeof(RT) == 4) {
                    const float4 r4 = *(const float4*)&res[gro];
                    rr[0] = r4.x; rr[1] = r4.y; rr[2] = r4.z; rr[3] = r4.w;
                } else {
                    const bf16x4 r4 = *(const bf16x4*)&res[gro];
                    #pragma unroll
                    for (int e = 0; e < 4; ++e) rr[e] = (float)r4[e];
                }
                v.x += bb.x + rr[0]; v.y += bb.y + rr[1];
                v.z += bb.z + rr[2]; v.w += bb.w + rr[3];
                *(float4*)&outf[gro] = v;
            }
        }
    }
}

// ---------------------------------------------------------------------------
// Attention stats: block = (window w = bid>>2, head quad q = bid&3), one head
// per wave. Partial |QK^T + 0.1*rpe| sums -> Mraw4[w*4+q] (deterministic).
// ---------------------------------------------------------------------------
__global__ __launch_bounds__(256)
void attn_stats(const bf16* __restrict__ qkv, const float* __restrict__ rpe,
                float* __restrict__ Mraw4, int idx) {
    __shared__ float lsum[4];
    const int bid = blockIdx.x;
    const int w = bid >> 2;
    const int tid = threadIdx.x, lane = tid & 63, wv = tid >> 6;
    const int h = (bid & 3) * 4 + wv;
    const int l15 = lane & 15, lg = lane >> 4;
    const long gbase = (idx == 0) ? (long)w * 64 : ((long)(w >> 6) * 4096 + (w & 63));
    const long gstride = (idx == 0) ? 1 : 64;
    bf16x8 kf[4];
    #pragma unroll
    for (int i = 0; i < 4; ++i) {
        const long gs = gbase + (long)(i * 16 + l15) * gstride;
        kf[i] = *(const bf16x8*)&qkv[gs * 1536 + 512 + h * 32 + lg * 8];
    }
    const float* rh = rpe + h * 4096;
    float asum = 0.f;
    #pragma unroll
    for (int mi = 0; mi < 4; ++mi) {
        const long gs = gbase + (long)(mi * 16 + l15) * gstride;
        const bf16x8 qf = *(const bf16x8*)&qkv[gs * 1536 + h * 32 + lg * 8];
        f32x4 sc[4] = {};
        #pragma unroll
        for (int ni = 0; ni < 4; ++ni) sc[ni] = mfma16(qf, kf[ni], sc[ni]);
        #pragma unroll
        for (int r = 0; r < 4; ++r) {
            const int srow = mi * 16 + lg * 4 + r;
            #pragma unroll
            for (int ni = 0; ni < 4; ++ni)
                asum += fabsf(sc[ni][r] + 0.1f * rh[srow * 64 + ni * 16 + l15]);
        }
    }
    #pragma unroll
    for (int m = 1; m < 64; m <<= 1) asum += __shfl_xor(asum, m);
    if (lane == 0) lsum[wv] = asum;
    __syncthreads();
    if (tid == 0) Mraw4[bid] = lsum[0] + lsum[1] + lsum[2] + lsum[3];
}

// ---------------------------------------------------------------------------
// Attention apply (with mcalc FOLDED IN: each block recomputes Mv[256] from
// Mraw4 -- max is rounding-exact so this is bit-deterministic across blocks).
// ---------------------------------------------------------------------------
template <typename XT>
__global__ __launch_bounds__(256)
void attn_apply(const bf16* __restrict__ qkv, const float* __restrict__ rpe,
                const float* __restrict__ Mraw4, const XT* __restrict__ xin,
                bf16* __restrict__ attout, int idx) {
    __shared__ __align__(16) bf16 lsP[4][64 * 64];
    __shared__ __align__(16) bf16 lsVt[4][32 * 64];
    __shared__ float Mvs[256];
    __shared__ float red[4];
    const int bid = blockIdx.x;
    const int w = bid >> 2;
    const int tid = threadIdx.x, lane = tid & 63, wv = tid >> 6;
    const int h = (bid & 3) * 4 + wv;
    const int l15 = lane & 15, lg = lane >> 4;
    const long gbase = (idx == 0) ? (long)w * 64 : ((long)(w >> 6) * 4096 + (w & 63));
    const long gstride = (idx == 0) ? 1 : 64;

    // ---- folded mcalc: Mvs[t] = max((sum4/65536)/max_all, 0.5) ----
    {
        const float v = (Mraw4[tid * 4] + Mraw4[tid * 4 + 1] +
                         Mraw4[tid * 4 + 2] + Mraw4[tid * 4 + 3]) *
                        (1.0f / 65536.0f);
        float m = v;
        #pragma unroll
        for (int msk = 1; msk < 64; msk <<= 1) m = fmaxf(m, __shfl_xor(m, msk));
        if (lane == 0) red[wv] = m;
        __syncthreads();
        const float mm = fmaxf(fmaxf(red[0], red[1]), fmaxf(red[2], red[3]));
        Mvs[tid] = fmaxf(v / mm, 0.5f);
        __syncthreads();
    }
    const float Mw = Mvs[w];
    bf16* P  = lsP[wv];
    bf16* Vt = lsVt[wv];

    {
        const int d4 = (lane & 7) * 4;
        #pragma unroll
        for (int it = 0; it < 8; ++it) {
            const int t = it * 8 + (lane >> 3);
            const bf16x4 v = *(const bf16x4*)
                &qkv[(gbase + (long)t * gstride) * 1536 + 1024 + h * 32 + d4];
            #pragma unroll
            for (int e = 0; e < 4; ++e) {
                const int d = d4 + e;
                Vt[d * 64 + (t ^ ((d & 7) * 8))] = v[e];
            }
        }
    }
    bf16x8 kf[4];
    #pragma unroll
    for (int i = 0; i < 4; ++i) {
        const long gs = gbase + (long)(i * 16 + l15) * gstride;
        kf[i] = *(const bf16x8*)&qkv[gs * 1536 + 512 + h * 32 + lg * 8];
    }
    const float* rh = rpe + h * 4096;
    #pragma unroll
    for (int mi = 0; mi < 4; ++mi) {
        const long gs = gbase + (long)(mi * 16 + l15) * gstride;
        const bf16x8 qf = *(const bf16x8*)&qkv[gs * 1536 + h * 32 + lg * 8];
        f32x4 sc[4] = {};
        #pragma unroll
        for (int ni = 0; ni < 4; ++ni) sc[ni] = mfma16(qf, kf[ni], sc[ni]);
        #pragma unroll
        for (int r = 0; r < 4; ++r) {
            const int srow = mi * 16 + lg * 4 + r;
            float vv[4], ssq = 0.f;
            #pragma unroll
            for (int ni = 0; ni < 4; ++ni) {
                const float v = sc[ni][r] + 0.1f * rh[srow * 64 + ni * 16 + l15];
                vv[ni] = v;
                ssq += v * v;
            }
            ssq += __shfl_xor(ssq, 1);
            ssq += __shfl_xor(ssq, 2);
            ssq += __shfl_xor(ssq, 4);
            ssq += __shfl_xor(ssq, 8);
            const float is = 1.0f / fmaxf(sqrtf(ssq), 1e-12f);
            #pragma unroll
            for (int ni = 0; ni < 4; ++ni) {
                const float v = (1.0f - __cosf(vv[ni] * is * 1.57079632679f)) * Mw;
                const int col = ni * 16 + l15;
                P[srow * 64 + (col ^ ((srow & 7) * 8))] = (bf16)v;
            }
        }
    }
    f32x4 acc[4][2] = {};
    #pragma unroll
    for (int kk = 0; kk < 2; ++kk) {
        bf16x8 bfr[2];
        #pragma unroll
        for (int dj = 0; dj < 2; ++dj) {
            const int d = dj * 16 + l15;
            bfr[dj] = *(const bf16x8*)&Vt[d * 64 + ((kk * 32 + lg * 8) ^ ((d & 7) * 8))];
        }
        #pragma unroll
        for (int mi = 0; mi < 4; ++mi) {
            const int s = mi * 16 + l15;
            const bf16x8 af = *(const bf16x8*)&P[s * 64 + ((kk * 32 + lg * 8) ^ ((s & 7) * 8))];
            #pragma unroll
            for (int dj = 0; dj < 2; ++dj)
                acc[mi][dj] = mfma16(af, bfr[dj], acc[mi][dj]);
        }
    }
    #pragma unroll
    for (int mi = 0; mi < 4; ++mi) {
        #pragma unroll
        for (int r = 0; r < 4; ++r) {
            const int s = mi * 16 + lg * 4 + r;
            const long gg = gbase + (long)s * gstride;
            const float rm = 1.0f - Mvs[(int)(gg >> 6)];
            #pragma unroll
            for (int dj = 0; dj < 2; ++dj) {
                const int d = dj * 16 + l15;
                const size_t oidx = (size_t)gg * 512 + h * 32 + d;
                attout[oidx] = (bf16)(acc[mi][dj][r] + (float)xin[oidx] * rm);
            }
        }
    }
}

// ---------------------------------------------------------------------------
// Host-side orchestration.  Residual spine is bf16 internally (XMID, X1);
// the final output write is fp32 into d_out.
// ---------------------------------------------------------------------------
extern "C" void kernel_launch(void* const* d_in, const int* in_sizes, int n_in,
                              void* d_out, int out_size, void* d_ws, size_t ws_size,
                              hipStream_t stream) {
    const float* x    = (const float*)d_in[0];
    const float* rpe0 = (const float*)d_in[1];
    const float* rpe1 = (const float*)d_in[2];
    auto W = [&](int i) { return (const float*)d_in[i]; };

    char* ws = (char*)d_ws;
    size_t off = 0;
    auto alloc = [&](size_t bytes) {
        void* p = ws + off;
        off += (bytes + 255) & ~(size_t)255;
        return p;
    };
    bf16 *wqkvT[2], *wprojT[2], *wfc1T[2], *wfc2T[2];
    for (int b = 0; b < 2; ++b) {
        wqkvT[b] = (bf16*)alloc((size_t)1536 * 512 * 2);
        wprojT[b] = (bf16*)alloc((size_t)512 * 512 * 2);
        wfc1T[b] = (bf16*)alloc((size_t)2048 * 512 * 2);
        wfc2T[b] = (bf16*)alloc((size_t)512 * 2048 * 2);
    }
    bf16* IMG = (bf16*)alloc((size_t)16384 * 512 * 2);
    bf16* QKV = (bf16*)alloc((size_t)16384 * 1536 * 2);
    bf16* ATT = (bf16*)alloc((size_t)16384 * 512 * 2);
    bf16* H1  = QKV;  // fc1 output [16384,2048] overlays QKV+ATT (both dead)
    bf16* XMID  = (bf16*)alloc((size_t)16384 * 512 * 2);  // bf16 spine
    bf16* X1    = (bf16*)alloc((size_t)16384 * 512 * 2);  // bf16 spine
    float* Mraw4 = (float*)alloc(1024 * 4);
    float* OUT   = (float*)d_out;

    // ---- fused weight transpose: all 8 in one launch ----
    TransArgs ta;
    const int widx[8] = {5, 6, 10, 12, 16, 17, 21, 23};
    bf16* wdst[8] = {wqkvT[0], wprojT[0], wfc1T[0], wfc2T[0],
                     wqkvT[1], wprojT[1], wfc1T[1], wfc2T[1]};
    const int wk[8] = {512, 512, 512, 2048, 512, 512, 512, 2048};
    const int wn[8] = {1536, 512, 2048, 512, 1536, 512, 2048, 512};
    int acc_b = 0;
    for (int i = 0; i < 8; ++i) {
        ta.W[i] = W(widx[i]);
        ta.Wt[i] = wdst[i];
        ta.K[i] = wk[i];
        ta.N[i] = wn[i];
        ta.blk0[i] = acc_b;
        acc_b += (wn[i] / 32) * (wk[i] / 32);
    }
    ta.blk0[8] = acc_b;
    transpose_all<<<acc_b, 256, 0, stream>>>(ta);

    for (int b = 0; b < 2; ++b) {
        const float* rpe = (b == 0) ? rpe0 : rpe1;
        const int base = (b == 0) ? 3 : 14;
        const float* ln1g = W(base + 0);
        const float* ln1b = W(base + 1);
        const float* bproj = W(base + 4);
        const float* ln2g = W(base + 5);
        const float* ln2b = W(base + 6);
        const float* bfc1 = W(base + 8);
        const float* bfc2 = W(base + 10);

        if (b == 0) {
            // xin = x (fp32)
            ln_kernel<float><<<4096, 256, 0, stream>>>(x, ln1g, ln1b, IMG);
            gemm_bt<0, 512, float><<<dim3(12, 128), 512, 0, stream>>>(
                IMG, wqkvT[0], 1536, 512, nullptr, nullptr, nullptr, QKV);
            attn_stats<<<1024, 256, 0, stream>>>(QKV, rpe, Mraw4, 0);
            attn_apply<float><<<1024, 256, 0, stream>>>(
                QKV, rpe, Mraw4, x, ATT, 0);
            // proj: +bias +res(x fp32) -> XMID (bf16)
            gemm_bt<3, 512, float><<<dim3(4, 128), 512, 0, stream>>>(
                ATT, wprojT[0], 512, 512, bproj, x, nullptr, XMID);
            ln_kernel<bf16><<<4096, 256, 0, stream>>>(XMID, ln2g, ln2b, IMG);
            gemm_bt<2, 512, float><<<dim3(16, 128), 512, 0, stream>>>(
                IMG, wfc1T[0], 2048, 512, bfc1, nullptr, nullptr, H1);
            // FC2: +bias +res(XMID bf16) -> X1 (bf16)
            gemm_bt<3, 0, bf16><<<dim3(4, 128), 512, 0, stream>>>(
                H1, wfc2T[0], 512, 2048, bfc2, XMID, nullptr, X1);
        } else {
            // xin = X1 (bf16)
            ln_kernel<bf16><<<4096, 256, 0, stream>>>(X1, ln1g, ln1b, IMG);
            gemm_bt<0, 512, float><<<dim3(12, 128), 512, 0, stream>>>(
                IMG, wqkvT[1], 1536, 512, nullptr, nullptr, nullptr, QKV);
            attn_stats<<<1024, 256, 0, stream>>>(QKV, rpe, Mraw4, 1);
            attn_apply<bf16><<<1024, 256, 0, stream>>>(
                QKV, rpe, Mraw4, X1, ATT, 1);
            gemm_bt<3, 512, bf16><<<dim3(4, 128), 512, 0, stream>>>(
                ATT, wprojT[1], 512, 512, bproj, X1, nullptr, XMID);
            ln_kernel<bf16><<<4096, 256, 0, stream>>>(XMID, ln2g, ln2b, IMG);
            gemm_bt<2, 512, float><<<dim3(16, 128), 512, 0, stream>>>(
                IMG, wfc1T[1], 2048, 512, bfc1, nullptr, nullptr, H1);
            // final FC2: +bias +res(XMID bf16) -> d_out (fp32)
            gemm_bt<1, 0, bf16><<<dim3(4, 128), 512, 0, stream>>>(
                H1, wfc2T[1], 512, 2048, bfc2, XMID, OUT, nullptr);
        }
    }
    (void)in_sizes; (void)n_in; (void)out_size; (void)ws_size;
}

// Round 17
// 434.435 us; speedup vs baseline: 1.0594x; 1.0594x over previous
//
#include <hip/hip_runtime.h>
#include <cstdint>
#include <cstddef>

typedef __bf16 bf16;
typedef __attribute__((ext_vector_type(4))) float f32x4;
typedef __attribute__((ext_vector_type(8))) __bf16 bf16x8;
typedef __attribute__((ext_vector_type(4))) __bf16 bf16x4;

static __device__ __forceinline__ f32x4 mfma16(bf16x8 a, bf16x8 b, f32x4 c) {
    return __builtin_amdgcn_mfma_f32_16x16x32_bf16(a, b, c, 0, 0, 0);
}

#define GLOAD_LDS16(gsrc, ldst)                                              \
    __builtin_amdgcn_global_load_lds(                                        \
        (const __attribute__((address_space(1))) void*)(gsrc),               \
        (__attribute__((address_space(3))) void*)(ldst), 16, 0, 0)

// ---------------------------------------------------------------------------
// Fused weight transpose + cast (all 8 weights in ONE launch).
// ---------------------------------------------------------------------------
struct TransArgs {
    const float* W[8];
    bf16* Wt[8];
    int K[8];
    int N[8];
    int blk0[9];
};

__global__ __launch_bounds__(256)
void transpose_all(TransArgs a) {
    __shared__ float tile[32][33];
    const int b = blockIdx.x;
    int j = 0;
    #pragma unroll
    for (int i = 0; i < 7; ++i)
        if (b >= a.blk0[i + 1]) j = i + 1;
    const int rel = b - a.blk0[j];
    const int K = a.K[j], N = a.N[j];
    const int nxb = N >> 5;
    const int n0 = (rel % nxb) * 32, k0 = (rel / nxb) * 32;
    const float* W = a.W[j];
    bf16* Wt = a.Wt[j];
    const int tx = threadIdx.x & 31, ty = threadIdx.x >> 5;
    #pragma unroll
    for (int i = ty; i < 32; i += 8)
        tile[i][tx] = W[(size_t)(k0 + i) * N + n0 + tx];
    __syncthreads();
    #pragma unroll
    for (int i = ty; i < 32; i += 8)
        Wt[(size_t)(n0 + i) * K + k0 + tx] = (bf16)tile[tx][i];
}

// ---------------------------------------------------------------------------
// LayerNorm over 512 cols, fp32 in -> bf16 out. 1 wave per row, 4 rows/block.
// ---------------------------------------------------------------------------
__global__ __launch_bounds__(256)
void ln_kernel(const float* __restrict__ x, const float* __restrict__ g,
               const float* __restrict__ b, bf16* __restrict__ out) {
    const int row = blockIdx.x * 4 + (threadIdx.x >> 6);
    const int lane = threadIdx.x & 63;
    const float* p = x + (size_t)row * 512 + lane * 8;
    const float4 a0 = *(const float4*)p;
    const float4 a1 = *(const float4*)(p + 4);
    float vx[8] = {a0.x, a0.y, a0.z, a0.w, a1.x, a1.y, a1.z, a1.w};
    float s = 0.f, ss = 0.f;
    #pragma unroll
    for (int k = 0; k < 8; ++k) { s += vx[k]; ss += vx[k] * vx[k]; }
    #pragma unroll
    for (int m = 1; m < 64; m <<= 1) {
        s  += __shfl_xor(s, m);
        ss += __shfl_xor(ss, m);
    }
    const float mean = s * (1.0f / 512.0f);
    const float var  = ss * (1.0f / 512.0f) - mean * mean;
    const float inv  = rsqrtf(var + 1e-5f);
    const int c0 = lane * 8;
    const float4 g0 = *(const float4*)&g[c0], g1 = *(const float4*)&g[c0 + 4];
    const float4 b0 = *(const float4*)&b[c0], b1 = *(const float4*)&b[c0 + 4];
    const float gv[8] = {g0.x, g0.y, g0.z, g0.w, g1.x, g1.y, g1.z, g1.w};
    const float bv[8] = {b0.x, b0.y, b0.z, b0.w, b1.x, b1.y, b1.z, b1.w};
    bf16x8 o;
    #pragma unroll
    for (int k = 0; k < 8; ++k)
        o[k] = (bf16)((vx[k] - mean) * inv * gv[k] + bv[k]);
    *(bf16x8*)&out[(size_t)row * 512 + c0] = o;
}

// ---------------------------------------------------------------------------
// GEMM: 128x128 tile, BK=32, 8 waves, per-wave 64x32 (acc[4][2], 32 VGPR),
// __launch_bounds__(512,8) -> 32 waves/CU. Hybrid K (static K=512 unroll /
// runtime loop for K=2048). gload_lds(16B) + source slot swizzle, XCD block
// swizzle. fp32 residual spine (R16's bf16 spine regressed: consumers are
// latency-bound, not BW-bound; extra converts + rounding cost more).
// Epilogues via per-wave [16][36] LDS bounce, vectorized.
// EPI 0: bf16. EPI 1: +bias +res(fp32) -> fp32. EPI 2: +bias GELU bf16.
// ---------------------------------------------------------------------------
template <int EPI, int KT>
__global__ __launch_bounds__(512, 8)
void gemm_bt(const bf16* __restrict__ A, const bf16* __restrict__ Bt,
             int N, int Krt, const float* __restrict__ bias,
             const float* __restrict__ res, float* __restrict__ outf,
             bf16* __restrict__ outh) {
    const int K = (KT > 0) ? KT : Krt;
    __shared__ __align__(16) bf16 smem[16384];
    auto lsA = [&](int buf) { return smem + buf * 4096; };
    auto lsB = [&](int buf) { return smem + 8192 + buf * 4096; };
    const int nx = gridDim.x;
    const int nwg = nx * gridDim.y;
    const int flat = blockIdx.y * nx + blockIdx.x;
    const int cpx = nwg >> 3;
    const int bswz = (flat & 7) * cpx + (flat >> 3);
    const int bn = bswz % nx, bm = bswz / nx;

    const int tid = threadIdx.x, lane = tid & 63, wv = tid >> 6;
    const int wr = wv >> 2, wc = wv & 3;
    const int l15 = lane & 15, lg = lane >> 4;
    const size_t abase = (size_t)bm * 128 * K;
    const size_t bbase = (size_t)bn * 128 * K;
    const int sr = wv * 16 + (lane >> 2);
    const int ks = ((lane & 3) ^ ((sr >> 1) & 3)) * 8;
    const bf16* aSrc = &A[abase + (size_t)sr * K + ks];
    const bf16* bSrc = &Bt[bbase + (size_t)sr * K + ks];

    f32x4 acc[4][2] = {};

    auto stage = [&](int buf, int kt) {
        GLOAD_LDS16(aSrc + kt, lsA(buf) + wv * 512);
        GLOAD_LDS16(bSrc + kt, lsB(buf) + wv * 512);
    };
    auto compute = [&](int buf) {
        bf16x8 af[4], bfr[2];
        #pragma unroll
        for (int i = 0; i < 4; ++i) {
            const int r = wr * 64 + i * 16 + l15;
            af[i] = *(const bf16x8*)
                (lsA(buf) + r * 32 + ((lg ^ ((r >> 1) & 3)) * 8));
        }
        #pragma unroll
        for (int j = 0; j < 2; ++j) {
            const int r = wc * 32 + j * 16 + l15;
            bfr[j] = *(const bf16x8*)
                (lsB(buf) + r * 32 + ((lg ^ ((r >> 1) & 3)) * 8));
        }
        #pragma unroll
        for (int i = 0; i < 4; ++i)
            #pragma unroll
            for (int j = 0; j < 2; ++j)
                acc[i][j] = mfma16(af[i], bfr[j], acc[i][j]);
    };

    if constexpr (KT > 0) {
        constexpr int NK = KT >> 5;
        stage(0, 0);
        __syncthreads();
        #pragma unroll
        for (int t = 0; t < NK - 1; ++t) {
            stage((t + 1) & 1, (t + 1) * 32);
            compute(t & 1);
            __syncthreads();
        }
        compute((NK - 1) & 1);
        __syncthreads();
    } else {
        const int NK = K >> 5;
        stage(0, 0);
        __syncthreads();
        int cur = 0;
        for (int t = 0; t < NK - 1; ++t) {
            stage(cur ^ 1, (t + 1) * 32);
            compute(cur);
            __syncthreads();
            cur ^= 1;
        }
        compute(cur);
        __syncthreads();
    }

    // ---- vectorized epilogue via per-wave LDS bounce ----
    float* lsW = (float*)smem + wv * 1024;   // [16][36]
    const int orow = bm * 128 + wr * 64;
    const int ocol = bn * 128 + wc * 32;
    #pragma unroll
    for (int i = 0; i < 4; ++i) {
        #pragma unroll
        for (int r = 0; r < 4; ++r)
            #pragma unroll
            for (int j = 0; j < 2; ++j)
                lsW[(lg * 4 + r) * 36 + j * 16 + l15] = acc[i][j][r];
        __builtin_amdgcn_s_waitcnt(0);   // lgkmcnt(0): same-wave visibility
        if constexpr (EPI == 0 || EPI == 2) {
            const int rl = lane >> 2, c8 = (lane & 3) * 8;
            const float4 v0 = *(const float4*)&lsW[rl * 36 + c8];
            const float4 v1 = *(const float4*)&lsW[rl * 36 + c8 + 4];
            float vv[8] = {v0.x, v0.y, v0.z, v0.w, v1.x, v1.y, v1.z, v1.w};
            if constexpr (EPI == 2) {
                const float4 bb0 = *(const float4*)&bias[ocol + c8];
                const float4 bb1 = *(const float4*)&bias[ocol + c8 + 4];
                const float bv[8] = {bb0.x, bb0.y, bb0.z, bb0.w,
                                     bb1.x, bb1.y, bb1.z, bb1.w};
                #pragma unroll
                for (int e = 0; e < 8; ++e) {
                    const float t = vv[e] + bv[e];
                    vv[e] = 0.5f * t * (1.0f + erff(t * 0.70710678118f));
                }
            }
            bf16x8 o;
            #pragma unroll
            for (int e = 0; e < 8; ++e) o[e] = (bf16)vv[e];
            *(bf16x8*)&outh[(size_t)(orow + i * 16 + rl) * N + ocol + c8] = o;
        } else {
            const int c4 = (lane & 7) * 4;
            const float4 bb = *(const float4*)&bias[ocol + c4];
            #pragma unroll
            for (int ii = 0; ii < 2; ++ii) {
                const int rl = ii * 8 + (lane >> 3);
                const size_t gro = (size_t)(orow + i * 16 + rl) * N + ocol + c4;
                float4 v = *(const float4*)&lsW[rl * 36 + c4];
                const float4 rr = *(const float4*)&res[gro];
                v.x += bb.x + rr.x; v.y += bb.y + rr.y;
                v.z += bb.z + rr.z; v.w += bb.w + rr.w;
                *(float4*)&outf[gro] = v;
            }
        }
    }
}

// ---------------------------------------------------------------------------
// Attention stats: block = (window w = bid>>2, head quad q = bid&3), one head
// per wave. Partial |QK^T + 0.1*rpe| sums -> Mraw4[w*4+q] (deterministic).
// ---------------------------------------------------------------------------
__global__ __launch_bounds__(256)
void attn_stats(const bf16* __restrict__ qkv, const float* __restrict__ rpe,
                float* __restrict__ Mraw4, int idx) {
    __shared__ float lsum[4];
    const int bid = blockIdx.x;
    const int w = bid >> 2;
    const int tid = threadIdx.x, lane = tid & 63, wv = tid >> 6;
    const int h = (bid & 3) * 4 + wv;
    const int l15 = lane & 15, lg = lane >> 4;
    const long gbase = (idx == 0) ? (long)w * 64 : ((long)(w >> 6) * 4096 + (w & 63));
    const long gstride = (idx == 0) ? 1 : 64;
    bf16x8 kf[4];
    #pragma unroll
    for (int i = 0; i < 4; ++i) {
        const long gs = gbase + (long)(i * 16 + l15) * gstride;
        kf[i] = *(const bf16x8*)&qkv[gs * 1536 + 512 + h * 32 + lg * 8];
    }
    const float* rh = rpe + h * 4096;
    float asum = 0.f;
    #pragma unroll
    for (int mi = 0; mi < 4; ++mi) {
        const long gs = gbase + (long)(mi * 16 + l15) * gstride;
        const bf16x8 qf = *(const bf16x8*)&qkv[gs * 1536 + h * 32 + lg * 8];
        f32x4 sc[4] = {};
        #pragma unroll
        for (int ni = 0; ni < 4; ++ni) sc[ni] = mfma16(qf, kf[ni], sc[ni]);
        #pragma unroll
        for (int r = 0; r < 4; ++r) {
            const int srow = mi * 16 + lg * 4 + r;
            #pragma unroll
            for (int ni = 0; ni < 4; ++ni)
                asum += fabsf(sc[ni][r] + 0.1f * rh[srow * 64 + ni * 16 + l15]);
        }
    }
    #pragma unroll
    for (int m = 1; m < 64; m <<= 1) asum += __shfl_xor(asum, m);
    if (lane == 0) lsum[wv] = asum;
    __syncthreads();
    if (tid == 0) Mraw4[bid] = lsum[0] + lsum[1] + lsum[2] + lsum[3];
}

// ---------------------------------------------------------------------------
// Attention apply with mcalc FOLDED IN: each block recomputes Mv[256] from
// Mraw4 in LDS (fixed-order 4-term sums + max/div are bit-reproducible
// across blocks). xin/res spine is fp32 (R15 config).
// ---------------------------------------------------------------------------
__global__ __launch_bounds__(256)
void attn_apply(const bf16* __restrict__ qkv, const float* __restrict__ rpe,
                const float* __restrict__ Mraw4, const float* __restrict__ xin,
                bf16* __restrict__ attout, int idx) {
    __shared__ __align__(16) bf16 lsP[4][64 * 64];
    __shared__ __align__(16) bf16 lsVt[4][32 * 64];
    __shared__ float Mvs[256];
    __shared__ float red[4];
    const int bid = blockIdx.x;
    const int w = bid >> 2;
    const int tid = threadIdx.x, lane = tid & 63, wv = tid >> 6;
    const int h = (bid & 3) * 4 + wv;
    const int l15 = lane & 15, lg = lane >> 4;
    const long gbase = (idx == 0) ? (long)w * 64 : ((long)(w >> 6) * 4096 + (w & 63));
    const long gstride = (idx == 0) ? 1 : 64;

    // ---- folded mcalc ----
    {
        const float v = (Mraw4[tid * 4] + Mraw4[tid * 4 + 1] +
                         Mraw4[tid * 4 + 2] + Mraw4[tid * 4 + 3]) *
                        (1.0f / 65536.0f);
        float m = v;
        #pragma unroll
        for (int msk = 1; msk < 64; msk <<= 1) m = fmaxf(m, __shfl_xor(m, msk));
        if (lane == 0) red[wv] = m;
        __syncthreads();
        const float mm = fmaxf(fmaxf(red[0], red[1]), fmaxf(red[2], red[3]));
        Mvs[tid] = fmaxf(v / mm, 0.5f);
        __syncthreads();
    }
    const float Mw = Mvs[w];
    bf16* P  = lsP[wv];
    bf16* Vt = lsVt[wv];

    {
        const int d4 = (lane & 7) * 4;
        #pragma unroll
        for (int it = 0; it < 8; ++it) {
            const int t = it * 8 + (lane >> 3);
            const bf16x4 v = *(const bf16x4*)
                &qkv[(gbase + (long)t * gstride) * 1536 + 1024 + h * 32 + d4];
            #pragma unroll
            for (int e = 0; e < 4; ++e) {
                const int d = d4 + e;
                Vt[d * 64 + (t ^ ((d & 7) * 8))] = v[e];
            }
        }
    }
    bf16x8 kf[4];
    #pragma unroll
    for (int i = 0; i < 4; ++i) {
        const long gs = gbase + (long)(i * 16 + l15) * gstride;
        kf[i] = *(const bf16x8*)&qkv[gs * 1536 + 512 + h * 32 + lg * 8];
    }
    const float* rh = rpe + h * 4096;
    #pragma unroll
    for (int mi = 0; mi < 4; ++mi) {
        const long gs = gbase + (long)(mi * 16 + l15) * gstride;
        const bf16x8 qf = *(const bf16x8*)&qkv[gs * 1536 + h * 32 + lg * 8];
        f32x4 sc[4] = {};
        #pragma unroll
        for (int ni = 0; ni < 4; ++ni) sc[ni] = mfma16(qf, kf[ni], sc[ni]);
        #pragma unroll
        for (int r = 0; r < 4; ++r) {
            const int srow = mi * 16 + lg * 4 + r;
            float vv[4], ssq = 0.f;
            #pragma unroll
            for (int ni = 0; ni < 4; ++ni) {
                const float v = sc[ni][r] + 0.1f * rh[srow * 64 + ni * 16 + l15];
                vv[ni] = v;
                ssq += v * v;
            }
            ssq += __shfl_xor(ssq, 1);
            ssq += __shfl_xor(ssq, 2);
            ssq += __shfl_xor(ssq, 4);
            ssq += __shfl_xor(ssq, 8);
            const float is = 1.0f / fmaxf(sqrtf(ssq), 1e-12f);
            #pragma unroll
            for (int ni = 0; ni < 4; ++ni) {
                const float v = (1.0f - __cosf(vv[ni] * is * 1.57079632679f)) * Mw;
                const int col = ni * 16 + l15;
                P[srow * 64 + (col ^ ((srow & 7) * 8))] = (bf16)v;
            }
        }
    }
    f32x4 acc[4][2] = {};
    #pragma unroll
    for (int kk = 0; kk < 2; ++kk) {
        bf16x8 bfr[2];
        #pragma unroll
        for (int dj = 0; dj < 2; ++dj) {
            const int d = dj * 16 + l15;
            bfr[dj] = *(const bf16x8*)&Vt[d * 64 + ((kk * 32 + lg * 8) ^ ((d & 7) * 8))];
        }
        #pragma unroll
        for (int mi = 0; mi < 4; ++mi) {
            const int s = mi * 16 + l15;
            const bf16x8 af = *(const bf16x8*)&P[s * 64 + ((kk * 32 + lg * 8) ^ ((s & 7) * 8))];
            #pragma unroll
            for (int dj = 0; dj < 2; ++dj)
                acc[mi][dj] = mfma16(af, bfr[dj], acc[mi][dj]);
        }
    }
    #pragma unroll
    for (int mi = 0; mi < 4; ++mi) {
        #pragma unroll
        for (int r = 0; r < 4; ++r) {
            const int s = mi * 16 + lg * 4 + r;
            const long gg = gbase + (long)s * gstride;
            const float rm = 1.0f - Mvs[(int)(gg >> 6)];
            #pragma unroll
            for (int dj = 0; dj < 2; ++dj) {
                const int d = dj * 16 + l15;
                const size_t oidx = (size_t)gg * 512 + h * 32 + d;
                attout[oidx] = (bf16)(acc[mi][dj][r] + xin[oidx] * rm);
            }
        }
    }
}

// ---------------------------------------------------------------------------
// Host-side orchestration (R15 fp32-spine config + folded mcalc).
// ---------------------------------------------------------------------------
extern "C" void kernel_launch(void* const* d_in, const int* in_sizes, int n_in,
                              void* d_out, int out_size, void* d_ws, size_t ws_size,
                              hipStream_t stream) {
    const float* x    = (const float*)d_in[0];
    const float* rpe0 = (const float*)d_in[1];
    const float* rpe1 = (const float*)d_in[2];
    auto W = [&](int i) { return (const float*)d_in[i]; };

    char* ws = (char*)d_ws;
    size_t off = 0;
    auto alloc = [&](size_t bytes) {
        void* p = ws + off;
        off += (bytes + 255) & ~(size_t)255;
        return p;
    };
    bf16 *wqkvT[2], *wprojT[2], *wfc1T[2], *wfc2T[2];
    for (int b = 0; b < 2; ++b) {
        wqkvT[b] = (bf16*)alloc((size_t)1536 * 512 * 2);
        wprojT[b] = (bf16*)alloc((size_t)512 * 512 * 2);
        wfc1T[b] = (bf16*)alloc((size_t)2048 * 512 * 2);
        wfc2T[b] = (bf16*)alloc((size_t)512 * 2048 * 2);
    }
    bf16* IMG = (bf16*)alloc((size_t)16384 * 512 * 2);
    bf16* QKV = (bf16*)alloc((size_t)16384 * 1536 * 2);
    bf16* ATT = (bf16*)alloc((size_t)16384 * 512 * 2);
    bf16* H1  = QKV;  // fc1 output [16384,2048] overlays QKV+ATT (both dead)
    float* X1    = (float*)alloc((size_t)16384 * 512 * 4);
    float* Mraw4 = (float*)alloc(1024 * 4);
    float* XMID  = (float*)d_out;  // fp32 spine lives in d_out

    // ---- fused weight transpose: all 8 in one launch ----
    TransArgs ta;
    const int widx[8] = {5, 6, 10, 12, 16, 17, 21, 23};
    bf16* wdst[8] = {wqkvT[0], wprojT[0], wfc1T[0], wfc2T[0],
                     wqkvT[1], wprojT[1], wfc1T[1], wfc2T[1]};
    const int wk[8] = {512, 512, 512, 2048, 512, 512, 512, 2048};
    const int wn[8] = {1536, 512, 2048, 512, 1536, 512, 2048, 512};
    int acc_b = 0;
    for (int i = 0; i < 8; ++i) {
        ta.W[i] = W(widx[i]);
        ta.Wt[i] = wdst[i];
        ta.K[i] = wk[i];
        ta.N[i] = wn[i];
        ta.blk0[i] = acc_b;
        acc_b += (wn[i] / 32) * (wk[i] / 32);
    }
    ta.blk0[8] = acc_b;
    transpose_all<<<acc_b, 256, 0, stream>>>(ta);

    for (int b = 0; b < 2; ++b) {
        const float* xin = (b == 0) ? x : X1;
        const float* rpe = (b == 0) ? rpe0 : rpe1;
        const int base = (b == 0) ? 3 : 14;
        const float* ln1g = W(base + 0);
        const float* ln1b = W(base + 1);
        const float* bproj = W(base + 4);
        const float* ln2g = W(base + 5);
        const float* ln2b = W(base + 6);
        const float* bfc1 = W(base + 8);
        const float* bfc2 = W(base + 10);

        // 1. LN1: xin -> IMG (bf16)
        ln_kernel<<<4096, 256, 0, stream>>>(xin, ln1g, ln1b, IMG);
        // 2. QKV GEMM (K=512 static): IMG @ wqkv -> QKV (bf16)
        gemm_bt<0, 512><<<dim3(12, 128), 512, 0, stream>>>(
            IMG, wqkvT[b], 1536, 512, nullptr, nullptr, nullptr, QKV);
        // 3. gating stats (mcalc folded into attn_apply)
        attn_stats<<<1024, 256, 0, stream>>>(QKV, rpe, Mraw4, b);
        // 4. attention apply -> ATT (bf16), includes masked residual
        attn_apply<<<1024, 256, 0, stream>>>(QKV, rpe, Mraw4, xin, ATT, b);
        // 5. proj GEMM (K=512 static): ATT @ wproj + bproj + xin -> XMID
        gemm_bt<1, 512><<<dim3(4, 128), 512, 0, stream>>>(
            ATT, wprojT[b], 512, 512, bproj, xin, XMID, nullptr);
        // 6. LN2: XMID -> IMG (bf16)
        ln_kernel<<<4096, 256, 0, stream>>>(XMID, ln2g, ln2b, IMG);
        // 7. FC1 + exact GELU (K=512 static): IMG @ wfc1 -> H1 (bf16)
        gemm_bt<2, 512><<<dim3(16, 128), 512, 0, stream>>>(
            IMG, wfc1T[b], 2048, 512, bfc1, nullptr, nullptr, H1);
        // 8. FC2 (K=2048 runtime): H1 @ wfc2 + bfc2 + XMID
        gemm_bt<1, 0><<<dim3(4, 128), 512, 0, stream>>>(
            H1, wfc2T[b], 512, 2048, bfc2, XMID, (b == 0) ? X1 : XMID, nullptr);
    }
    (void)in_sizes; (void)n_in; (void)out_size; (void)ws_size;
}